// Round 1
// baseline (5001.118 us; speedup 1.0000x reference)
//
#include <hip/hip_runtime.h>

// HMM forward (CgpHmmLayer): B=64, T=4096, S=305.
// One workgroup per batch element (64 WGs, 512 threads = 8 waves).
// Transition matrix (row-softmaxed) cached in registers:
//   wave w owns rows [40w, 40w+40); lane l owns cols {l, l+64, ..., l+256}.
//   areg[40][5] = 200 VGPRs/thread -> launch_bounds(512,2) (<=256 VGPR, 2 waves/SIMD).
// Per step: readlane-broadcast alpha (40 readlane, 200 FMA), partial column sums
// via ping-pong LDS buffer, ONE barrier/step; each wave gathers its own 40 columns
// (= its rows for the next step) so alpha stays in registers.
// Normalize every 8 steps; log(s) telescopes exactly. Init softmax normalizer
// folded into a final -log(Z_I).

constexpr int NS  = 305;   // states
constexpr int NSP = 320;   // padded states
constexpr int NT  = 4096;  // time steps
constexpr int NW  = 8;     // waves per block
constexpr int RPW = 40;    // rows per wave (NSP/NW)
constexpr int CPT = 5;     // cols per thread (NSP/64)
constexpr int NORM_MASK = 7; // normalize every 8 steps

__global__ __launch_bounds__(512, 2)
void hmm_fwd(const float* __restrict__ inputs,
             const float* __restrict__ initk,
             const float* __restrict__ transk,
             const float* __restrict__ emisk,
             float* __restrict__ out)
{
    __shared__ float sBm[4 * NSP];          // emission probs, [obs][state], padded 0
    __shared__ float sI[NSP];               // exp(init_kernel), padded 0
    __shared__ float sRowsum[NSP];          // per-row sum of exp(trans)
    __shared__ unsigned char sObs[NT];      // observation indices for this batch
    __shared__ float sPart[2][NW * NSP];    // ping-pong partial column sums
    __shared__ float sN[16];                // small reduce buffer (ping-pong 8+8)

    const int tid = threadIdx.x;
    const int w   = tid >> 6;   // wave id 0..7
    const int l   = tid & 63;   // lane id
    const int b   = blockIdx.x; // batch element

    // ---- zero-init padded LDS regions ----
    for (int i = tid; i < 4 * NSP; i += 512) sBm[i] = 0.f;
    for (int i = tid; i < NSP;     i += 512) sI[i]  = 0.f;
    __syncthreads();

    // ---- decode one-hot observations for this batch (coalesced float4) ----
    const float4* oh = (const float4*)(inputs + (size_t)b * NT * 4);
    #pragma unroll
    for (int i = 0; i < NT / 512; ++i) {
        int t = tid + i * 512;
        float4 v = oh[t];
        sObs[t] = (unsigned char)(int)(v.y + 2.f * v.z + 3.f * v.w + 0.5f);
    }

    // ---- emission softmax over 4 (per state) ----
    if (tid < NS) {
        float4 ek = ((const float4*)emisk)[tid];
        float e0 = __expf(ek.x), e1 = __expf(ek.y), e2 = __expf(ek.z), e3 = __expf(ek.w);
        float inv = 1.f / (e0 + e1 + e2 + e3);
        sBm[0 * NSP + tid] = e0 * inv;
        sBm[1 * NSP + tid] = e1 * inv;
        sBm[2 * NSP + tid] = e2 * inv;
        sBm[3 * NSP + tid] = e3 * inv;
    }

    // ---- init vector: exp only; normalizer Z_I folded at the end ----
    if (tid < NS) sI[tid] = __expf(initk[tid]);

    // ---- transition row sums: wave w handles rows w, w+8, ... (coalesced) ----
    for (int j = 0; j < RPW; ++j) {
        int r = w + j * NW;
        float part = 0.f;
        if (r < NS) {
            #pragma unroll
            for (int k = 0; k < CPT; ++k) {
                int c = l + 64 * k;
                if (c < NS) part += __expf(transk[r * NS + c]);
            }
        }
        #pragma unroll
        for (int off = 32; off; off >>= 1) part += __shfl_xor(part, off, 64);
        if (l == 0) sRowsum[r] = part;   // rows >= NS get 0 (guarded out later)
    }
    __syncthreads();

    // ---- log(Z_I): reduce sI over all states ----
    float v0 = (tid < NSP) ? sI[tid] : 0.f;
    #pragma unroll
    for (int off = 32; off; off >>= 1) v0 += __shfl_xor(v0, off, 64);
    if (l == 0) sN[w] = v0;
    __syncthreads();
    float z = 0.f;
    #pragma unroll
    for (int i = 0; i < 8; ++i) z += sN[i];
    const float logZI = __logf(z);
    __syncthreads();   // sN safe for reuse

    // ---- load register-cached, row-normalized transition slice ----
    float areg[RPW][CPT];
    #pragma unroll
    for (int j = 0; j < RPW; ++j) {
        const int row = w * RPW + j;
        const float invr = (row < NS) ? 1.f / sRowsum[row] : 0.f;
        #pragma unroll
        for (int k = 0; k < CPT; ++k) {
            const int col = l + 64 * k;
            float v = 0.f;
            if (row < NS && col < NS)
                v = __expf(transk[row * NS + col]) * invr;
            areg[j][k] = v;
        }
    }

    // ---- t = 0: alpha0 (unnormalized) = exp(init) * e0, kept in registers ----
    float va = 0.f;
    {
        int o0 = sObs[0];
        int col = w * RPW + l;
        if (l < RPW) va = sI[col] * sBm[o0 * NSP + col];
    }
    float ll = 0.f;

    // ---- main scan ----
    for (int t = 1; t < NT; ++t) {
        // prefetch emission for the columns this wave will gather (indep. of barrier)
        const int o = sObs[t];
        const float ecol = (l < RPW) ? sBm[o * NSP + w * RPW + l] : 0.f;

        // matvec: acc[c] += alpha[row] * A[row][c], alpha broadcast via readlane
        float acc[CPT] = {0.f, 0.f, 0.f, 0.f, 0.f};
        #pragma unroll
        for (int j = 0; j < RPW; ++j) {
            float sa = __uint_as_float(
                __builtin_amdgcn_readlane(__float_as_uint(va), j));
            #pragma unroll
            for (int k = 0; k < CPT; ++k)
                acc[k] = fmaf(sa, areg[j][k], acc[k]);
        }

        // write partial column sums (ping-pong buffer -> single barrier per step)
        float* pb = sPart[t & 1];
        #pragma unroll
        for (int k = 0; k < CPT; ++k)
            pb[w * NSP + l + 64 * k] = acc[k];
        __syncthreads();

        // gather: each wave assembles the 40 columns that are its rows next step
        if (l < RPW) {
            const int col = w * RPW + l;
            float s8 = 0.f;
            #pragma unroll
            for (int ww = 0; ww < NW; ++ww) s8 += pb[ww * NSP + col];
            va = s8 * ecol;
        } else {
            va = 0.f;
        }

        // periodic normalization + log-likelihood accumulation
        if ((t & NORM_MASK) == NORM_MASK) {
            float v = (l < RPW) ? va : 0.f;
            #pragma unroll
            for (int off = 32; off; off >>= 1) v += __shfl_xor(v, off, 64);
            const int nb = (t >> 3) & 1;
            if (l == 0) sN[nb * 8 + w] = v;
            __syncthreads();
            float tot = 0.f;
            #pragma unroll
            for (int i = 0; i < 8; ++i) tot += sN[nb * 8 + i];
            ll += __logf(tot);
            va *= 1.f / tot;
        }
    }

    if (tid == 0) out[b] = ll - logZI;
}

extern "C" void kernel_launch(void* const* d_in, const int* in_sizes, int n_in,
                              void* d_out, int out_size, void* d_ws, size_t ws_size,
                              hipStream_t stream) {
    const float* inputs = (const float*)d_in[0];
    const float* initk  = (const float*)d_in[1];
    const float* transk = (const float*)d_in[2];
    const float* emisk  = (const float*)d_in[3];
    hipLaunchKernelGGL(hmm_fwd, dim3(64), dim3(512), 0, stream,
                       inputs, initk, transk, emisk, (float*)d_out);
}